// Round 2
// baseline (486.393 us; speedup 1.0000x reference)
//
#include <hip/hip_runtime.h>

typedef unsigned int uint32;
typedef unsigned short ushort16;

#define DI __device__ __forceinline__

// ---- constants -------------------------------------------------------------
// B=2048, N_src=1, N_ngh=128, D_MODEL=FEAT=256, H=4, D_K=64, TEMP=8
#define BATCH 2048
#define NN    128
#define DM    256
#define NH    4
#define DK    64

// f32 -> bf16 (round to nearest even)
DI ushort16 f2bf(float f) {
    uint32 u = __float_as_uint(f);
    uint32 r = u + 0x7fffu + ((u >> 16) & 1u);
    return (ushort16)(r >> 16);
}

// unpack 8 bf16 (as uint4) -> 8 f32
DI void unpack8(const uint4 v, float f[8]) {
    f[0] = __uint_as_float(v.x << 16);
    f[1] = __uint_as_float(v.x & 0xffff0000u);
    f[2] = __uint_as_float(v.y << 16);
    f[3] = __uint_as_float(v.y & 0xffff0000u);
    f[4] = __uint_as_float(v.z << 16);
    f[5] = __uint_as_float(v.z & 0xffff0000u);
    f[6] = __uint_as_float(v.w << 16);
    f[7] = __uint_as_float(v.w & 0xffff0000u);
}

DI float dot8(const float* a, const float f[8], float acc) {
    acc = fmaf(a[0], f[0], acc);
    acc = fmaf(a[1], f[1], acc);
    acc = fmaf(a[2], f[2], acc);
    acc = fmaf(a[3], f[3], acc);
    acc = fmaf(a[4], f[4], acc);
    acc = fmaf(a[5], f[5], acc);
    acc = fmaf(a[6], f[6], acc);
    acc = fmaf(a[7], f[7], acc);
    return acc;
}

DI float dot4f(const float* a, const float4 w, float acc) {
    acc = fmaf(a[0], w.x, acc);
    acc = fmaf(a[1], w.y, acc);
    acc = fmaf(a[2], w.z, acc);
    acc = fmaf(a[3], w.w, acc);
    return acc;
}

// ---- kernel 1: u[b,h,:] = (src[b] @ w_qs^T)[h,:] @ w_ks_h  (scaled 1/TEMP) --
// grid 512, block 256, 4 batch rows per block
__global__ __launch_bounds__(256) void qu_kernel(
    const float* __restrict__ src, const float* __restrict__ wqs,
    const float* __restrict__ wks, float* __restrict__ u)
{
    __shared__ float sS[4][DM];   // src rows
    __shared__ float sQ[4][DM];   // q rows
    const int t  = threadIdx.x;
    const int b0 = blockIdx.x * 4;

    #pragma unroll
    for (int r = 0; r < 4; ++r) sS[r][t] = src[(size_t)(b0 + r) * DM + t];
    __syncthreads();

    // q[r][t] = sum_c sS[r][c] * wqs[t*256+c]
    {
        float acc[4] = {0.f, 0.f, 0.f, 0.f};
        const float* wrow = wqs + (size_t)t * DM;
        for (int kc = 0; kc < DM; kc += 4) {
            float4 w4 = *(const float4*)(wrow + kc);
            #pragma unroll
            for (int r = 0; r < 4; ++r) acc[r] = dot4f(&sS[r][kc], w4, acc[r]);
        }
        #pragma unroll
        for (int r = 0; r < 4; ++r) sQ[r][t] = acc[r];
    }
    __syncthreads();

    // u[r][h][t] = sum_d sQ[r][h*64+d] * wks[(h*64+d)*256 + t]
    for (int h = 0; h < NH; ++h) {
        float ua[4] = {0.f, 0.f, 0.f, 0.f};
        for (int dc = 0; dc < DK; dc += 8) {
            float q8[4][8];
            #pragma unroll
            for (int r = 0; r < 4; ++r) {
                #pragma unroll
                for (int e = 0; e < 8; ++e) q8[r][e] = sQ[r][h * DK + dc + e];
            }
            #pragma unroll
            for (int e = 0; e < 8; ++e) {
                float w = wks[(size_t)(h * DK + dc + e) * DM + t];
                #pragma unroll
                for (int r = 0; r < 4; ++r) ua[r] = fmaf(q8[r][e], w, ua[r]);
            }
        }
        #pragma unroll
        for (int r = 0; r < 4; ++r)
            u[(size_t)(b0 + r) * (NH * DM) + h * DM + t] = ua[r] * 0.125f;
    }
}

// ---- kernel 2: per-b attention: scores -> mask -> softmax -> pooled c ------
// grid 2048, block 256. seq staged to LDS as bf16 (f32 accumulation).
#define SEQ_STRIDE 264   // 256 + 8 pad; 528B rows stay 16B-aligned

__global__ __launch_bounds__(256) void attn_kernel(
    const float* __restrict__ seq, const int* __restrict__ mask,
    const float* __restrict__ u, float* __restrict__ c,
    float* __restrict__ attn_out)
{
    __shared__ ushort16 sseq[NN * SEQ_STRIDE];   // 67584 B
    __shared__ float    sbuf[2048];              // u (first 1024), then c-partials
    __shared__ float    sattn[NN * NH];          // [n][h]: n*4+h

    const int t = threadIdx.x;
    const int b = blockIdx.x;

    // load u[b] (1024 f32)
    #pragma unroll
    for (int i = 0; i < 4; ++i)
        sbuf[i * 256 + t] = u[(size_t)b * 1024 + i * 256 + t];

    // stage seq[b] (128x256 f32) into LDS as bf16, padded rows
    const float* sp = seq + (size_t)b * (NN * DM);
    #pragma unroll
    for (int it = 0; it < 32; ++it) {
        int idx = it * 1024 + t * 4;
        int row = idx >> 8, col = idx & 255;
        float4 v = *(const float4*)(sp + idx);
        uint2 pk;
        pk.x = (uint32)f2bf(v.x) | ((uint32)f2bf(v.y) << 16);
        pk.y = (uint32)f2bf(v.z) | ((uint32)f2bf(v.w) << 16);
        *(uint2*)&sseq[row * SEQ_STRIDE + col] = pk;
    }
    __syncthreads();

    // scores: thread handles (hA, n) and (hA+2, n)
    {
        const int n  = t & 127;
        const int hA = t >> 7;          // 0 or 1
        const float* uA = &sbuf[hA * 256];
        const float* uB = &sbuf[(hA + 2) * 256];
        float s0 = 0.f, s1 = 0.f;
        const ushort16* srow = &sseq[n * SEQ_STRIDE];
        for (int kc = 0; kc < DM; kc += 8) {
            uint4 v = *(const uint4*)(srow + kc);
            float f[8]; unpack8(v, f);
            s0 = dot8(&uA[kc], f, s0);
            s1 = dot8(&uB[kc], f, s1);
        }
        // mask rows: (4b+h) mod 2048  (reference's head-major tiling)
        int mrA = (4 * b + hA) & (BATCH - 1);
        int mrB = (4 * b + hA + 2) & (BATCH - 1);
        if (mask[(size_t)mrA * NN + n] != 0) s0 = -1e10f;
        if (mask[(size_t)mrB * NN + n] != 0) s1 = -1e10f;
        sattn[n * 4 + hA]     = s0;
        sattn[n * 4 + hA + 2] = s1;
    }
    __syncthreads();

    // softmax: wave w handles head w; lanes hold n=l and n=l+64
    {
        const int w = t >> 6, l = t & 63;
        float x0 = sattn[l * 4 + w], x1 = sattn[(l + 64) * 4 + w];
        float mx = fmaxf(x0, x1);
        #pragma unroll
        for (int o = 32; o > 0; o >>= 1) mx = fmaxf(mx, __shfl_xor(mx, o, 64));
        float e0 = __expf(x0 - mx), e1 = __expf(x1 - mx);
        float sm = e0 + e1;
        #pragma unroll
        for (int o = 32; o > 0; o >>= 1) sm += __shfl_xor(sm, o, 64);
        float inv = 1.f / sm;
        float a0 = e0 * inv, a1 = e1 * inv;
        sattn[l * 4 + w]        = a0;
        sattn[(l + 64) * 4 + w] = a1;
        attn_out[(size_t)b * (NH * NN) + w * NN + l]      = a0;
        attn_out[(size_t)b * (NH * NN) + w * NN + l + 64] = a1;
    }
    __syncthreads();

    // pooled c[h][j] = sum_n attn[h][n] * seq[n][j]; n split in 2 halves
    {
        const int ng = t >> 7;       // n-half
        const int jp = t & 127;      // column pair (cols 2jp, 2jp+1)
        float cc[4][2] = {{0.f,0.f},{0.f,0.f},{0.f,0.f},{0.f,0.f}};
        for (int i = 0; i < 64; ++i) {
            int n = ng * 64 + i;
            uint32 v = *(const uint32*)&sseq[n * SEQ_STRIDE + jp * 2];
            float f0 = __uint_as_float(v << 16);
            float f1 = __uint_as_float(v & 0xffff0000u);
            float4 at = *(const float4*)&sattn[n * 4];
            cc[0][0] = fmaf(at.x, f0, cc[0][0]); cc[0][1] = fmaf(at.x, f1, cc[0][1]);
            cc[1][0] = fmaf(at.y, f0, cc[1][0]); cc[1][1] = fmaf(at.y, f1, cc[1][1]);
            cc[2][0] = fmaf(at.z, f0, cc[2][0]); cc[2][1] = fmaf(at.z, f1, cc[2][1]);
            cc[3][0] = fmaf(at.w, f0, cc[3][0]); cc[3][1] = fmaf(at.w, f1, cc[3][1]);
        }
        __syncthreads();   // everyone past u/sattn reads before sbuf recycle
        #pragma unroll
        for (int h = 0; h < 4; ++h) {
            sbuf[ng * 1024 + h * 256 + jp * 2]     = cc[h][0];
            sbuf[ng * 1024 + h * 256 + jp * 2 + 1] = cc[h][1];
        }
    }
    __syncthreads();
    #pragma unroll
    for (int h = 0; h < 4; ++h)
        c[(size_t)b * 1024 + h * 256 + t] = sbuf[h * 256 + t] + sbuf[1024 + h * 256 + t];
}

// ---- kernel 3: v-proj + fc + residual + LN + fc1(relu) + fc2 ---------------
// grid 256, block 256, 8 rows per block (halves L2 weight re-fetch vs 4)
__global__ __launch_bounds__(256) void mlp_kernel(
    const float* __restrict__ c, const float* __restrict__ src,
    const float* __restrict__ wvs, const float* __restrict__ fcw,
    const float* __restrict__ fcb, const float* __restrict__ lng,
    const float* __restrict__ lnb, const float* __restrict__ fc1w,
    const float* __restrict__ fc1b, const float* __restrict__ fc2w,
    const float* __restrict__ fc2b, float* __restrict__ zout)
{
    __shared__ float sC[8][1024];   // pooled c rows (32 KB)
    __shared__ float sA[8][256];    // attention out rows
    __shared__ float sX[8][256];    // normalized x
    __shared__ float sS[8][256];    // src rows
    __shared__ float sH[8][256];    // relu(fc1) rows
    __shared__ float sRed[4][8][2]; // [wave][row][{sum, sumsq}]

    const int t  = threadIdx.x;
    const int b0 = blockIdx.x * 8;
    const int h  = t >> 6;          // head for stage A (uniform per wave)

    #pragma unroll
    for (int i = 0; i < 8; ++i)
        *(float4*)&sC[i][t * 4] = *(const float4*)&c[(size_t)(b0 + i) * 1024 + t * 4];
    #pragma unroll
    for (int r = 0; r < 8; ++r) sS[r][t] = src[(size_t)(b0 + r) * DM + t];
    __syncthreads();

    // stage A: out_attn[r][t] = dot(c[r][h*256 + :], wvs[t*256 + :])
    {
        float acc[8] = {0.f,0.f,0.f,0.f,0.f,0.f,0.f,0.f};
        const float* wr = wvs + (size_t)t * DM;
        for (int kc = 0; kc < DM; kc += 4) {
            float4 w4 = *(const float4*)(wr + kc);
            #pragma unroll
            for (int r = 0; r < 8; ++r) acc[r] = dot4f(&sC[r][h * 256 + kc], w4, acc[r]);
        }
        #pragma unroll
        for (int r = 0; r < 8; ++r) sA[r][t] = acc[r];
    }
    __syncthreads();

    // stage B: x = out_attn @ fcw^T + fcb + src ; then LayerNorm
    float xv[8];
    {
        float acc[8] = {0.f,0.f,0.f,0.f,0.f,0.f,0.f,0.f};
        const float* wr = fcw + (size_t)t * DM;
        for (int kc = 0; kc < DM; kc += 4) {
            float4 w4 = *(const float4*)(wr + kc);
            #pragma unroll
            for (int r = 0; r < 8; ++r) acc[r] = dot4f(&sA[r][kc], w4, acc[r]);
        }
        float bb = fcb[t];
        #pragma unroll
        for (int r = 0; r < 8; ++r) xv[r] = acc[r] + bb + sS[r][t];
    }
    {
        const int w = t >> 6, l = t & 63;
        #pragma unroll
        for (int r = 0; r < 8; ++r) {
            float vs = xv[r], vq = xv[r] * xv[r];
            #pragma unroll
            for (int o = 32; o > 0; o >>= 1) {
                vs += __shfl_xor(vs, o, 64);
                vq += __shfl_xor(vq, o, 64);
            }
            if (l == 0) { sRed[w][r][0] = vs; sRed[w][r][1] = vq; }
        }
        __syncthreads();
        float g = lng[t], bb = lnb[t];
        #pragma unroll
        for (int r = 0; r < 8; ++r) {
            float S = sRed[0][r][0] + sRed[1][r][0] + sRed[2][r][0] + sRed[3][r][0];
            float Q = sRed[0][r][1] + sRed[1][r][1] + sRed[2][r][1] + sRed[3][r][1];
            float mu  = S * (1.f / 256.f);
            float var = Q * (1.f / 256.f) - mu * mu;
            float rs  = rsqrtf(var + 1e-5f);
            sX[r][t] = (xv[r] - mu) * rs * g + bb;
        }
    }
    __syncthreads();

    // stage C: h1 = relu([x | src] @ fc1w^T + fc1b)
    {
        float acc[8] = {0.f,0.f,0.f,0.f,0.f,0.f,0.f,0.f};
        const float* wr = fc1w + (size_t)t * 512;
        for (int kc = 0; kc < 256; kc += 4) {
            float4 w4 = *(const float4*)(wr + kc);
            #pragma unroll
            for (int r = 0; r < 8; ++r) acc[r] = dot4f(&sX[r][kc], w4, acc[r]);
        }
        for (int kc = 0; kc < 256; kc += 4) {
            float4 w4 = *(const float4*)(wr + 256 + kc);
            #pragma unroll
            for (int r = 0; r < 8; ++r) acc[r] = dot4f(&sS[r][kc], w4, acc[r]);
        }
        float bb = fc1b[t];
        #pragma unroll
        for (int r = 0; r < 8; ++r) sH[r][t] = fmaxf(acc[r] + bb, 0.f);
    }
    __syncthreads();

    // stage D: z = h1 @ fc2w^T + fc2b
    {
        float acc[8] = {0.f,0.f,0.f,0.f,0.f,0.f,0.f,0.f};
        const float* wr = fc2w + (size_t)t * DM;
        for (int kc = 0; kc < DM; kc += 4) {
            float4 w4 = *(const float4*)(wr + kc);
            #pragma unroll
            for (int r = 0; r < 8; ++r) acc[r] = dot4f(&sH[r][kc], w4, acc[r]);
        }
        float bb = fc2b[t];
        #pragma unroll
        for (int r = 0; r < 8; ++r)
            zout[(size_t)(b0 + r) * DM + t] = acc[r] + bb;
    }
}

// ---- launch ----------------------------------------------------------------
extern "C" void kernel_launch(void* const* d_in, const int* in_sizes, int n_in,
                              void* d_out, int out_size, void* d_ws, size_t ws_size,
                              hipStream_t stream)
{
    const float* src  = (const float*)d_in[0];
    const float* seq  = (const float*)d_in[1];
    const int*   mask = (const int*)d_in[2];
    const float* wqs  = (const float*)d_in[3];
    const float* wks  = (const float*)d_in[4];
    const float* wvs  = (const float*)d_in[5];
    const float* fcw  = (const float*)d_in[6];
    const float* fcb  = (const float*)d_in[7];
    const float* lng  = (const float*)d_in[8];
    const float* lnb  = (const float*)d_in[9];
    const float* fc1w = (const float*)d_in[10];
    const float* fc1b = (const float*)d_in[11];
    const float* fc2w = (const float*)d_in[12];
    const float* fc2b = (const float*)d_in[13];

    float* zout     = (float*)d_out;
    float* attn_out = zout + (size_t)BATCH * DM;      // z first, then attn

    float* u = (float*)d_ws;                          // 2048*1024 f32 = 8 MB
    float* c = u + (size_t)BATCH * 1024;              // 2048*1024 f32 = 8 MB

    qu_kernel<<<512, 256, 0, stream>>>(src, wqs, wks, u);
    attn_kernel<<<BATCH, 256, 0, stream>>>(seq, mask, u, c, attn_out);
    mlp_kernel<<<256, 256, 0, stream>>>(c, src, wvs, fcw, fcb, lng, lnb,
                                        fc1w, fc1b, fc2w, fc2b, zout);
}

// Round 3
// 481.290 us; speedup vs baseline: 1.0106x; 1.0106x over previous
//
#include <hip/hip_runtime.h>

typedef unsigned int uint32;
typedef unsigned short ushort16;

#define DI __device__ __forceinline__

// ---- constants -------------------------------------------------------------
// B=2048, N_src=1, N_ngh=128, D_MODEL=FEAT=256, H=4, D_K=64, TEMP=8
#define BATCH 2048
#define NN    128
#define DM    256
#define NH    4
#define DK    64

// f32 -> bf16 (round to nearest even)
DI ushort16 f2bf(float f) {
    uint32 u = __float_as_uint(f);
    uint32 r = u + 0x7fffu + ((u >> 16) & 1u);
    return (ushort16)(r >> 16);
}

// unpack 8 bf16 (as uint4) -> 8 f32
DI void unpack8(const uint4 v, float f[8]) {
    f[0] = __uint_as_float(v.x << 16);
    f[1] = __uint_as_float(v.x & 0xffff0000u);
    f[2] = __uint_as_float(v.y << 16);
    f[3] = __uint_as_float(v.y & 0xffff0000u);
    f[4] = __uint_as_float(v.z << 16);
    f[5] = __uint_as_float(v.z & 0xffff0000u);
    f[6] = __uint_as_float(v.w << 16);
    f[7] = __uint_as_float(v.w & 0xffff0000u);
}

DI float dot8(const float* a, const float f[8], float acc) {
    acc = fmaf(a[0], f[0], acc);
    acc = fmaf(a[1], f[1], acc);
    acc = fmaf(a[2], f[2], acc);
    acc = fmaf(a[3], f[3], acc);
    acc = fmaf(a[4], f[4], acc);
    acc = fmaf(a[5], f[5], acc);
    acc = fmaf(a[6], f[6], acc);
    acc = fmaf(a[7], f[7], acc);
    return acc;
}

DI float dot4f(const float* a, const float4 w, float acc) {
    acc = fmaf(a[0], w.x, acc);
    acc = fmaf(a[1], w.y, acc);
    acc = fmaf(a[2], w.z, acc);
    acc = fmaf(a[3], w.w, acc);
    return acc;
}

// ---- kernel 1: u[b,h,:] = (src[b] @ w_qs^T)[h,:] @ w_ks_h  (scaled 1/TEMP) --
// grid 256, block 256, 8 batch rows per block (amortize weight reads + FMA)
__global__ __launch_bounds__(256) void qu_kernel(
    const float* __restrict__ src, const float* __restrict__ wqs,
    const float* __restrict__ wks, float* __restrict__ u)
{
    __shared__ float sS[8][DM];   // src rows
    __shared__ float sQ[8][DM];   // q rows
    const int t  = threadIdx.x;
    const int b0 = blockIdx.x * 8;

    #pragma unroll
    for (int r = 0; r < 8; ++r) sS[r][t] = src[(size_t)(b0 + r) * DM + t];
    __syncthreads();

    // q[r][t] = sum_c sS[r][c] * wqs[t*256+c]
    {
        float acc[8] = {0.f,0.f,0.f,0.f,0.f,0.f,0.f,0.f};
        const float* wrow = wqs + (size_t)t * DM;
        for (int kc = 0; kc < DM; kc += 4) {
            float4 w4 = *(const float4*)(wrow + kc);
            #pragma unroll
            for (int r = 0; r < 8; ++r) acc[r] = dot4f(&sS[r][kc], w4, acc[r]);
        }
        #pragma unroll
        for (int r = 0; r < 8; ++r) sQ[r][t] = acc[r];
    }
    __syncthreads();

    // u[r][h][t] = sum_d sQ[r][h*64+d] * wks[(h*64+d)*256 + t]
    for (int h = 0; h < NH; ++h) {
        float ua[8] = {0.f,0.f,0.f,0.f,0.f,0.f,0.f,0.f};
        for (int dc = 0; dc < DK; dc += 8) {
            float wv[8];
            #pragma unroll
            for (int e = 0; e < 8; ++e)
                wv[e] = wks[(size_t)(h * DK + dc + e) * DM + t];
            #pragma unroll
            for (int r = 0; r < 8; ++r) {
                float4 qa = *(const float4*)&sQ[r][h * DK + dc];
                float4 qb = *(const float4*)&sQ[r][h * DK + dc + 4];
                float a = ua[r];
                a = fmaf(qa.x, wv[0], a); a = fmaf(qa.y, wv[1], a);
                a = fmaf(qa.z, wv[2], a); a = fmaf(qa.w, wv[3], a);
                a = fmaf(qb.x, wv[4], a); a = fmaf(qb.y, wv[5], a);
                a = fmaf(qb.z, wv[6], a); a = fmaf(qb.w, wv[7], a);
                ua[r] = a;
            }
        }
        #pragma unroll
        for (int r = 0; r < 8; ++r)
            u[(size_t)(b0 + r) * (NH * DM) + h * DM + t] = ua[r] * 0.125f;
    }
}

// ---- kernel 2: per-b attention: scores -> mask -> softmax -> pooled c ------
// grid 2048, block 256. seq staged to LDS as bf16 (f32 accumulation).
// LDS total 77.8 KB -> 2 blocks/CU (inter-block memory/compute overlap).
#define SEQ_STRIDE 264   // 256 + 8 pad; 528B rows stay 16B-aligned
#define U_STRIDE   264   // u rows padded: banks {0,8,16,24} across h -> no conflict

__global__ __launch_bounds__(256) void attn_kernel(
    const float* __restrict__ seq, const int* __restrict__ mask,
    const float* __restrict__ u, float* __restrict__ c,
    float* __restrict__ attn_out)
{
    __shared__ ushort16 sseq[NN * SEQ_STRIDE];   // 67584 B
    __shared__ float    sbuf[2048];              // u (padded, first 1056) then c-partials
    __shared__ float    sattn[NN * NH];          // [n][h]: n*4+h

    const int t = threadIdx.x;
    const int b = blockIdx.x;

    // load u[b] (1024 f32) into padded rows of sbuf
    #pragma unroll
    for (int i = 0; i < 4; ++i)
        sbuf[i * U_STRIDE + t] = u[(size_t)b * 1024 + i * 256 + t];

    // stage seq[b] (128x256 f32) into LDS as bf16, padded rows
    const float* sp = seq + (size_t)b * (NN * DM);
    #pragma unroll
    for (int it = 0; it < 32; ++it) {
        int idx = it * 1024 + t * 4;
        int row = idx >> 8, col = idx & 255;
        float4 v = *(const float4*)(sp + idx);
        uint2 pk;
        pk.x = (uint32)f2bf(v.x) | ((uint32)f2bf(v.y) << 16);
        pk.y = (uint32)f2bf(v.z) | ((uint32)f2bf(v.w) << 16);
        *(uint2*)&sseq[row * SEQ_STRIDE + col] = pk;
    }
    __syncthreads();

    // scores: 4-lane groups share a seq row (LDS broadcast); h = t&3.
    // Per wave: 16 distinct rows -> 2 addrs/bank (free); u reads conflict-free
    // via U_STRIDE pad.
    {
        const int h  = t & 3;
        const int n0 = t >> 2;            // 0..63
        const float* uh = &sbuf[h * U_STRIDE];
        const ushort16* r0 = &sseq[n0 * SEQ_STRIDE];
        const ushort16* r1 = &sseq[(n0 + 64) * SEQ_STRIDE];
        float s0 = 0.f, s1 = 0.f;
        for (int kc = 0; kc < DM; kc += 8) {
            uint4 va = *(const uint4*)(r0 + kc);
            uint4 vb = *(const uint4*)(r1 + kc);
            float fa[8], fb[8];
            unpack8(va, fa); unpack8(vb, fb);
            s0 = dot8(&uh[kc], fa, s0);
            s1 = dot8(&uh[kc], fb, s1);
        }
        // mask rows: (4b+h) mod 2048  (reference's head-major tiling)
        int mr = (4 * b + h) & (BATCH - 1);
        if (mask[(size_t)mr * NN + n0] != 0)      s0 = -1e10f;
        if (mask[(size_t)mr * NN + n0 + 64] != 0) s1 = -1e10f;
        sattn[n0 * 4 + h]        = s0;
        sattn[(n0 + 64) * 4 + h] = s1;
    }
    __syncthreads();

    // softmax: wave w handles head w; lanes hold n=l and n=l+64
    {
        const int w = t >> 6, l = t & 63;
        float x0 = sattn[l * 4 + w], x1 = sattn[(l + 64) * 4 + w];
        float mx = fmaxf(x0, x1);
        #pragma unroll
        for (int o = 32; o > 0; o >>= 1) mx = fmaxf(mx, __shfl_xor(mx, o, 64));
        float e0 = __expf(x0 - mx), e1 = __expf(x1 - mx);
        float sm = e0 + e1;
        #pragma unroll
        for (int o = 32; o > 0; o >>= 1) sm += __shfl_xor(sm, o, 64);
        float inv = 1.f / sm;
        float a0 = e0 * inv, a1 = e1 * inv;
        sattn[l * 4 + w]        = a0;
        sattn[(l + 64) * 4 + w] = a1;
        attn_out[(size_t)b * (NH * NN) + w * NN + l]      = a0;
        attn_out[(size_t)b * (NH * NN) + w * NN + l + 64] = a1;
    }
    __syncthreads();

    // pooled c[h][j] = sum_n attn[h][n] * seq[n][j]; n split in 2 halves
    {
        const int ng = t >> 7;       // n-half
        const int jp = t & 127;      // column pair (cols 2jp, 2jp+1)
        float cc[4][2] = {{0.f,0.f},{0.f,0.f},{0.f,0.f},{0.f,0.f}};
        for (int i = 0; i < 64; ++i) {
            int n = ng * 64 + i;
            uint32 v = *(const uint32*)&sseq[n * SEQ_STRIDE + jp * 2];
            float f0 = __uint_as_float(v << 16);
            float f1 = __uint_as_float(v & 0xffff0000u);
            float4 at = *(const float4*)&sattn[n * 4];
            cc[0][0] = fmaf(at.x, f0, cc[0][0]); cc[0][1] = fmaf(at.x, f1, cc[0][1]);
            cc[1][0] = fmaf(at.y, f0, cc[1][0]); cc[1][1] = fmaf(at.y, f1, cc[1][1]);
            cc[2][0] = fmaf(at.z, f0, cc[2][0]); cc[2][1] = fmaf(at.z, f1, cc[2][1]);
            cc[3][0] = fmaf(at.w, f0, cc[3][0]); cc[3][1] = fmaf(at.w, f1, cc[3][1]);
        }
        __syncthreads();   // all u/sattn-dependent reads done; recycle sbuf
        #pragma unroll
        for (int h = 0; h < 4; ++h) {
            sbuf[ng * 1024 + h * 256 + jp * 2]     = cc[h][0];
            sbuf[ng * 1024 + h * 256 + jp * 2 + 1] = cc[h][1];
        }
    }
    __syncthreads();
    #pragma unroll
    for (int h = 0; h < 4; ++h)
        c[(size_t)b * 1024 + h * 256 + t] = sbuf[h * 256 + t] + sbuf[1024 + h * 256 + t];
}

// ---- kernel 3: v-proj + fc + residual + LN + fc1(relu) + fc2 ---------------
// grid 256, block 256, 8 rows per block
__global__ __launch_bounds__(256) void mlp_kernel(
    const float* __restrict__ c, const float* __restrict__ src,
    const float* __restrict__ wvs, const float* __restrict__ fcw,
    const float* __restrict__ fcb, const float* __restrict__ lng,
    const float* __restrict__ lnb, const float* __restrict__ fc1w,
    const float* __restrict__ fc1b, const float* __restrict__ fc2w,
    const float* __restrict__ fc2b, float* __restrict__ zout)
{
    __shared__ float sC[8][1024];   // pooled c rows (32 KB)
    __shared__ float sA[8][256];    // attention out rows
    __shared__ float sX[8][256];    // normalized x
    __shared__ float sS[8][256];    // src rows
    __shared__ float sH[8][256];    // relu(fc1) rows
    __shared__ float sRed[4][8][2]; // [wave][row][{sum, sumsq}]

    const int t  = threadIdx.x;
    const int b0 = blockIdx.x * 8;
    const int h  = t >> 6;          // head for stage A (uniform per wave)

    #pragma unroll
    for (int i = 0; i < 8; ++i)
        *(float4*)&sC[i][t * 4] = *(const float4*)&c[(size_t)(b0 + i) * 1024 + t * 4];
    #pragma unroll
    for (int r = 0; r < 8; ++r) sS[r][t] = src[(size_t)(b0 + r) * DM + t];
    __syncthreads();

    // stage A: out_attn[r][t] = dot(c[r][h*256 + :], wvs[t*256 + :])
    {
        float acc[8] = {0.f,0.f,0.f,0.f,0.f,0.f,0.f,0.f};
        const float* wr = wvs + (size_t)t * DM;
        for (int kc = 0; kc < DM; kc += 4) {
            float4 w4 = *(const float4*)(wr + kc);
            #pragma unroll
            for (int r = 0; r < 8; ++r) acc[r] = dot4f(&sC[r][h * 256 + kc], w4, acc[r]);
        }
        #pragma unroll
        for (int r = 0; r < 8; ++r) sA[r][t] = acc[r];
    }
    __syncthreads();

    // stage B: x = out_attn @ fcw^T + fcb + src ; then LayerNorm
    float xv[8];
    {
        float acc[8] = {0.f,0.f,0.f,0.f,0.f,0.f,0.f,0.f};
        const float* wr = fcw + (size_t)t * DM;
        for (int kc = 0; kc < DM; kc += 4) {
            float4 w4 = *(const float4*)(wr + kc);
            #pragma unroll
            for (int r = 0; r < 8; ++r) acc[r] = dot4f(&sA[r][kc], w4, acc[r]);
        }
        float bb = fcb[t];
        #pragma unroll
        for (int r = 0; r < 8; ++r) xv[r] = acc[r] + bb + sS[r][t];
    }
    {
        const int w = t >> 6, l = t & 63;
        #pragma unroll
        for (int r = 0; r < 8; ++r) {
            float vs = xv[r], vq = xv[r] * xv[r];
            #pragma unroll
            for (int o = 32; o > 0; o >>= 1) {
                vs += __shfl_xor(vs, o, 64);
                vq += __shfl_xor(vq, o, 64);
            }
            if (l == 0) { sRed[w][r][0] = vs; sRed[w][r][1] = vq; }
        }
        __syncthreads();
        float g = lng[t], bb = lnb[t];
        #pragma unroll
        for (int r = 0; r < 8; ++r) {
            float S = sRed[0][r][0] + sRed[1][r][0] + sRed[2][r][0] + sRed[3][r][0];
            float Q = sRed[0][r][1] + sRed[1][r][1] + sRed[2][r][1] + sRed[3][r][1];
            float mu  = S * (1.f / 256.f);
            float var = Q * (1.f / 256.f) - mu * mu;
            float rs  = rsqrtf(var + 1e-5f);
            sX[r][t] = (xv[r] - mu) * rs * g + bb;
        }
    }
    __syncthreads();

    // stage C: h1 = relu([x | src] @ fc1w^T + fc1b)
    {
        float acc[8] = {0.f,0.f,0.f,0.f,0.f,0.f,0.f,0.f};
        const float* wr = fc1w + (size_t)t * 512;
        for (int kc = 0; kc < 256; kc += 4) {
            float4 w4 = *(const float4*)(wr + kc);
            #pragma unroll
            for (int r = 0; r < 8; ++r) acc[r] = dot4f(&sX[r][kc], w4, acc[r]);
        }
        for (int kc = 0; kc < 256; kc += 4) {
            float4 w4 = *(const float4*)(wr + 256 + kc);
            #pragma unroll
            for (int r = 0; r < 8; ++r) acc[r] = dot4f(&sS[r][kc], w4, acc[r]);
        }
        float bb = fc1b[t];
        #pragma unroll
        for (int r = 0; r < 8; ++r) sH[r][t] = fmaxf(acc[r] + bb, 0.f);
    }
    __syncthreads();

    // stage D: z = h1 @ fc2w^T + fc2b
    {
        float acc[8] = {0.f,0.f,0.f,0.f,0.f,0.f,0.f,0.f};
        const float* wr = fc2w + (size_t)t * DM;
        for (int kc = 0; kc < DM; kc += 4) {
            float4 w4 = *(const float4*)(wr + kc);
            #pragma unroll
            for (int r = 0; r < 8; ++r) acc[r] = dot4f(&sH[r][kc], w4, acc[r]);
        }
        float bb = fc2b[t];
        #pragma unroll
        for (int r = 0; r < 8; ++r)
            zout[(size_t)(b0 + r) * DM + t] = acc[r] + bb;
    }
}

// ---- launch ----------------------------------------------------------------
extern "C" void kernel_launch(void* const* d_in, const int* in_sizes, int n_in,
                              void* d_out, int out_size, void* d_ws, size_t ws_size,
                              hipStream_t stream)
{
    const float* src  = (const float*)d_in[0];
    const float* seq  = (const float*)d_in[1];
    const int*   mask = (const int*)d_in[2];
    const float* wqs  = (const float*)d_in[3];
    const float* wks  = (const float*)d_in[4];
    const float* wvs  = (const float*)d_in[5];
    const float* fcw  = (const float*)d_in[6];
    const float* fcb  = (const float*)d_in[7];
    const float* lng  = (const float*)d_in[8];
    const float* lnb  = (const float*)d_in[9];
    const float* fc1w = (const float*)d_in[10];
    const float* fc1b = (const float*)d_in[11];
    const float* fc2w = (const float*)d_in[12];
    const float* fc2b = (const float*)d_in[13];

    float* zout     = (float*)d_out;
    float* attn_out = zout + (size_t)BATCH * DM;      // z first, then attn

    float* u = (float*)d_ws;                          // 2048*1024 f32 = 8 MB
    float* c = u + (size_t)BATCH * 1024;              // 2048*1024 f32 = 8 MB

    qu_kernel<<<256, 256, 0, stream>>>(src, wqs, wks, u);
    attn_kernel<<<BATCH, 256, 0, stream>>>(seq, mask, u, c, attn_out);
    mlp_kernel<<<256, 256, 0, stream>>>(c, src, wvs, fcw, fcb, lng, lnb,
                                        fc1w, fc1b, fc2w, fc2b, zout);
}

// Round 4
// 471.856 us; speedup vs baseline: 1.0308x; 1.0200x over previous
//
#include <hip/hip_runtime.h>

typedef unsigned int uint32;
typedef unsigned short ushort16;

#define DI __device__ __forceinline__

// ---- constants -------------------------------------------------------------
// B=2048, N_src=1, N_ngh=128, D_MODEL=FEAT=256, H=4, D_K=64, TEMP=8
#define BATCH 2048
#define NN    128
#define DM    256
#define NH    4
#define DK    64

// bf16 (as ushort) -> f32
DI float bf2f(ushort16 h) { return __uint_as_float(((uint32)h) << 16); }

// f32 -> bf16 (round to nearest even)
DI ushort16 f2bf(float f) {
    uint32 u = __float_as_uint(f);
    uint32 r = u + 0x7fffu + ((u >> 16) & 1u);
    return (ushort16)(r >> 16);
}

// unpack 8 bf16 (as uint4) -> 8 f32
DI void unpack8(const uint4 v, float f[8]) {
    f[0] = __uint_as_float(v.x << 16);
    f[1] = __uint_as_float(v.x & 0xffff0000u);
    f[2] = __uint_as_float(v.y << 16);
    f[3] = __uint_as_float(v.y & 0xffff0000u);
    f[4] = __uint_as_float(v.z << 16);
    f[5] = __uint_as_float(v.z & 0xffff0000u);
    f[6] = __uint_as_float(v.w << 16);
    f[7] = __uint_as_float(v.w & 0xffff0000u);
}

DI float dot8(const float* a, const float f[8], float acc) {
    acc = fmaf(a[0], f[0], acc);
    acc = fmaf(a[1], f[1], acc);
    acc = fmaf(a[2], f[2], acc);
    acc = fmaf(a[3], f[3], acc);
    acc = fmaf(a[4], f[4], acc);
    acc = fmaf(a[5], f[5], acc);
    acc = fmaf(a[6], f[6], acc);
    acc = fmaf(a[7], f[7], acc);
    return acc;
}

// ---- weight layout in d_ws bf16 area (element offsets) ---------------------
#define WOFF_QS  0
#define WOFF_KS  65536
#define WOFF_VS  131072
#define WOFF_FC  196608
#define WOFF_FC1 262144
#define WOFF_FC2 393216
// total 458752 bf16 elements

// ---- kernel 0: convert all weight matrices to bf16 in d_ws -----------------
// grid 448, block 256; each block converts 1024 elements
__global__ __launch_bounds__(256) void prep_kernel(
    const float* __restrict__ wqs, const float* __restrict__ wks,
    const float* __restrict__ wvs, const float* __restrict__ fcw,
    const float* __restrict__ fc1w, const float* __restrict__ fc2w,
    ushort16* __restrict__ out)
{
    const int bid = blockIdx.x;
    const float* srcp; size_t soff, doff;
    if (bid < 64)       { srcp = wqs;  soff = (size_t)bid * 1024;         doff = WOFF_QS;  }
    else if (bid < 128) { srcp = wks;  soff = (size_t)(bid - 64) * 1024;  doff = WOFF_KS;  }
    else if (bid < 192) { srcp = wvs;  soff = (size_t)(bid - 128) * 1024; doff = WOFF_VS;  }
    else if (bid < 256) { srcp = fcw;  soff = (size_t)(bid - 192) * 1024; doff = WOFF_FC;  }
    else if (bid < 384) { srcp = fc1w; soff = (size_t)(bid - 256) * 1024; doff = WOFF_FC1; }
    else                { srcp = fc2w; soff = (size_t)(bid - 384) * 1024; doff = WOFF_FC2; }
    const int t = threadIdx.x;
    float4 v = *(const float4*)(srcp + soff + t * 4);
    uint2 pk;
    pk.x = (uint32)f2bf(v.x) | ((uint32)f2bf(v.y) << 16);
    pk.y = (uint32)f2bf(v.z) | ((uint32)f2bf(v.w) << 16);
    *(uint2*)(out + doff + soff + t * 4) = pk;
}

// ---- kernel 1: u[b,h,:] = (src[b] @ w_qs^T)[h,:] @ w_ks_h  (scaled 1/TEMP) --
// grid 256, block 256, 8 batch rows per block; bf16 weights
__global__ __launch_bounds__(256) void qu_kernel(
    const float* __restrict__ src, const ushort16* __restrict__ wbf,
    float* __restrict__ u)
{
    __shared__ float sS[8][DM];   // src rows
    __shared__ float sQ[8][DM];   // q rows
    const int t  = threadIdx.x;
    const int b0 = blockIdx.x * 8;

    #pragma unroll
    for (int r = 0; r < 8; ++r) sS[r][t] = src[(size_t)(b0 + r) * DM + t];
    __syncthreads();

    // q[r][t] = sum_c sS[r][c] * wqs[t*256+c]
    {
        float acc[8] = {0.f,0.f,0.f,0.f,0.f,0.f,0.f,0.f};
        const ushort16* wrow = wbf + WOFF_QS + (size_t)t * DM;
        for (int kc = 0; kc < DM; kc += 8) {
            uint4 w8 = *(const uint4*)(wrow + kc);
            float wf[8]; unpack8(w8, wf);
            #pragma unroll
            for (int r = 0; r < 8; ++r) acc[r] = dot8(&sS[r][kc], wf, acc[r]);
        }
        #pragma unroll
        for (int r = 0; r < 8; ++r) sQ[r][t] = acc[r];
    }
    __syncthreads();

    // u[r][h][t] = sum_d sQ[r][h*64+d] * wks[(h*64+d)*256 + t]
    const ushort16* wks = wbf + WOFF_KS;
    for (int h = 0; h < NH; ++h) {
        float ua[8] = {0.f,0.f,0.f,0.f,0.f,0.f,0.f,0.f};
        for (int dc = 0; dc < DK; dc += 8) {
            float wv[8];
            #pragma unroll
            for (int e = 0; e < 8; ++e)
                wv[e] = bf2f(wks[(size_t)(h * DK + dc + e) * DM + t]);
            #pragma unroll
            for (int r = 0; r < 8; ++r) {
                float4 qa = *(const float4*)&sQ[r][h * DK + dc];
                float4 qb = *(const float4*)&sQ[r][h * DK + dc + 4];
                float a = ua[r];
                a = fmaf(qa.x, wv[0], a); a = fmaf(qa.y, wv[1], a);
                a = fmaf(qa.z, wv[2], a); a = fmaf(qa.w, wv[3], a);
                a = fmaf(qb.x, wv[4], a); a = fmaf(qb.y, wv[5], a);
                a = fmaf(qb.z, wv[6], a); a = fmaf(qb.w, wv[7], a);
                ua[r] = a;
            }
        }
        #pragma unroll
        for (int r = 0; r < 8; ++r)
            u[(size_t)(b0 + r) * (NH * DM) + h * DM + t] = ua[r] * 0.125f;
    }
}

// ---- kernel 2: per-b attention: scores -> mask -> softmax -> pooled c ------
// grid 2048, block 256. seq staged to LDS as bf16 (f32 accumulation).
// LDS total 77.8 KB -> 2 blocks/CU (inter-block memory/compute overlap).
#define SEQ_STRIDE 264   // 256 + 8 pad; 528B rows stay 16B-aligned
#define U_STRIDE   264   // u rows padded: banks {0,8,16,24} across h -> no conflict

__global__ __launch_bounds__(256) void attn_kernel(
    const float* __restrict__ seq, const int* __restrict__ mask,
    const float* __restrict__ u, float* __restrict__ c,
    float* __restrict__ attn_out)
{
    __shared__ ushort16 sseq[NN * SEQ_STRIDE];   // 67584 B
    __shared__ float    sbuf[2048];              // u (padded) then c-partials
    __shared__ float    sattn[NN * NH];          // [n][h]: n*4+h

    const int t = threadIdx.x;
    const int b = blockIdx.x;

    // load u[b] (1024 f32) into padded rows of sbuf
    #pragma unroll
    for (int i = 0; i < 4; ++i)
        sbuf[i * U_STRIDE + t] = u[(size_t)b * 1024 + i * 256 + t];

    // stage seq[b] (128x256 f32) into LDS as bf16, padded rows
    const float* sp = seq + (size_t)b * (NN * DM);
    #pragma unroll
    for (int it = 0; it < 32; ++it) {
        int idx = it * 1024 + t * 4;
        int row = idx >> 8, col = idx & 255;
        float4 v = *(const float4*)(sp + idx);
        uint2 pk;
        pk.x = (uint32)f2bf(v.x) | ((uint32)f2bf(v.y) << 16);
        pk.y = (uint32)f2bf(v.z) | ((uint32)f2bf(v.w) << 16);
        *(uint2*)&sseq[row * SEQ_STRIDE + col] = pk;
    }
    __syncthreads();

    // scores: 4-lane groups share a seq row (LDS broadcast); h = t&3.
    {
        const int h  = t & 3;
        const int n0 = t >> 2;            // 0..63
        const float* uh = &sbuf[h * U_STRIDE];
        const ushort16* r0 = &sseq[n0 * SEQ_STRIDE];
        const ushort16* r1 = &sseq[(n0 + 64) * SEQ_STRIDE];
        float s0 = 0.f, s1 = 0.f;
        for (int kc = 0; kc < DM; kc += 8) {
            uint4 va = *(const uint4*)(r0 + kc);
            uint4 vb = *(const uint4*)(r1 + kc);
            float fa[8], fb[8];
            unpack8(va, fa); unpack8(vb, fb);
            s0 = dot8(&uh[kc], fa, s0);
            s1 = dot8(&uh[kc], fb, s1);
        }
        // mask rows: (4b+h) mod 2048  (reference's head-major tiling)
        int mr = (4 * b + h) & (BATCH - 1);
        if (mask[(size_t)mr * NN + n0] != 0)      s0 = -1e10f;
        if (mask[(size_t)mr * NN + n0 + 64] != 0) s1 = -1e10f;
        sattn[n0 * 4 + h]        = s0;
        sattn[(n0 + 64) * 4 + h] = s1;
    }
    __syncthreads();

    // softmax: wave w handles head w; lanes hold n=l and n=l+64
    {
        const int w = t >> 6, l = t & 63;
        float x0 = sattn[l * 4 + w], x1 = sattn[(l + 64) * 4 + w];
        float mx = fmaxf(x0, x1);
        #pragma unroll
        for (int o = 32; o > 0; o >>= 1) mx = fmaxf(mx, __shfl_xor(mx, o, 64));
        float e0 = __expf(x0 - mx), e1 = __expf(x1 - mx);
        float sm = e0 + e1;
        #pragma unroll
        for (int o = 32; o > 0; o >>= 1) sm += __shfl_xor(sm, o, 64);
        float inv = 1.f / sm;
        float a0 = e0 * inv, a1 = e1 * inv;
        sattn[l * 4 + w]        = a0;
        sattn[(l + 64) * 4 + w] = a1;
        attn_out[(size_t)b * (NH * NN) + w * NN + l]      = a0;
        attn_out[(size_t)b * (NH * NN) + w * NN + l + 64] = a1;
    }
    __syncthreads();

    // pooled c[h][j] = sum_n attn[h][n] * seq[n][j]; n split in 2 halves
    {
        const int ng = t >> 7;       // n-half
        const int jp = t & 127;      // column pair (cols 2jp, 2jp+1)
        float cc[4][2] = {{0.f,0.f},{0.f,0.f},{0.f,0.f},{0.f,0.f}};
        for (int i = 0; i < 64; ++i) {
            int n = ng * 64 + i;
            uint32 v = *(const uint32*)&sseq[n * SEQ_STRIDE + jp * 2];
            float f0 = __uint_as_float(v << 16);
            float f1 = __uint_as_float(v & 0xffff0000u);
            float4 at = *(const float4*)&sattn[n * 4];
            cc[0][0] = fmaf(at.x, f0, cc[0][0]); cc[0][1] = fmaf(at.x, f1, cc[0][1]);
            cc[1][0] = fmaf(at.y, f0, cc[1][0]); cc[1][1] = fmaf(at.y, f1, cc[1][1]);
            cc[2][0] = fmaf(at.z, f0, cc[2][0]); cc[2][1] = fmaf(at.z, f1, cc[2][1]);
            cc[3][0] = fmaf(at.w, f0, cc[3][0]); cc[3][1] = fmaf(at.w, f1, cc[3][1]);
        }
        __syncthreads();   // all u/sattn-dependent reads done; recycle sbuf
        #pragma unroll
        for (int h = 0; h < 4; ++h) {
            sbuf[ng * 1024 + h * 256 + jp * 2]     = cc[h][0];
            sbuf[ng * 1024 + h * 256 + jp * 2 + 1] = cc[h][1];
        }
    }
    __syncthreads();
    #pragma unroll
    for (int h = 0; h < 4; ++h)
        c[(size_t)b * 1024 + h * 256 + t] = sbuf[h * 256 + t] + sbuf[1024 + h * 256 + t];
}

// ---- kernel 3: v-proj + fc + residual + LN + fc1(relu) + fc2 ---------------
// grid 256, block 256, 8 rows per block; bf16 weights
__global__ __launch_bounds__(256) void mlp_kernel(
    const float* __restrict__ c, const float* __restrict__ src,
    const ushort16* __restrict__ wbf,
    const float* __restrict__ fcb, const float* __restrict__ lng,
    const float* __restrict__ lnb, const float* __restrict__ fc1b,
    const float* __restrict__ fc2b, float* __restrict__ zout)
{
    __shared__ float sC[8][1024];   // pooled c rows (32 KB)
    __shared__ float sA[8][256];    // attention out rows
    __shared__ float sX[8][256];    // normalized x
    __shared__ float sS[8][256];    // src rows
    __shared__ float sH[8][256];    // relu(fc1) rows
    __shared__ float sRed[4][8][2]; // [wave][row][{sum, sumsq}]

    const int t  = threadIdx.x;
    const int b0 = blockIdx.x * 8;
    const int h  = t >> 6;          // head for stage A (uniform per wave)

    #pragma unroll
    for (int i = 0; i < 8; ++i)
        *(float4*)&sC[i][t * 4] = *(const float4*)&c[(size_t)(b0 + i) * 1024 + t * 4];
    #pragma unroll
    for (int r = 0; r < 8; ++r) sS[r][t] = src[(size_t)(b0 + r) * DM + t];
    __syncthreads();

    // stage A: out_attn[r][t] = dot(c[r][h*256 + :], wvs[t*256 + :])
    {
        float acc[8] = {0.f,0.f,0.f,0.f,0.f,0.f,0.f,0.f};
        const ushort16* wr = wbf + WOFF_VS + (size_t)t * DM;
        for (int kc = 0; kc < DM; kc += 8) {
            uint4 w8 = *(const uint4*)(wr + kc);
            float wf[8]; unpack8(w8, wf);
            #pragma unroll
            for (int r = 0; r < 8; ++r) acc[r] = dot8(&sC[r][h * 256 + kc], wf, acc[r]);
        }
        #pragma unroll
        for (int r = 0; r < 8; ++r) sA[r][t] = acc[r];
    }
    __syncthreads();

    // stage B: x = out_attn @ fcw^T + fcb + src ; then LayerNorm
    float xv[8];
    {
        float acc[8] = {0.f,0.f,0.f,0.f,0.f,0.f,0.f,0.f};
        const ushort16* wr = wbf + WOFF_FC + (size_t)t * DM;
        for (int kc = 0; kc < DM; kc += 8) {
            uint4 w8 = *(const uint4*)(wr + kc);
            float wf[8]; unpack8(w8, wf);
            #pragma unroll
            for (int r = 0; r < 8; ++r) acc[r] = dot8(&sA[r][kc], wf, acc[r]);
        }
        float bb = fcb[t];
        #pragma unroll
        for (int r = 0; r < 8; ++r) xv[r] = acc[r] + bb + sS[r][t];
    }
    {
        const int w = t >> 6, l = t & 63;
        #pragma unroll
        for (int r = 0; r < 8; ++r) {
            float vs = xv[r], vq = xv[r] * xv[r];
            #pragma unroll
            for (int o = 32; o > 0; o >>= 1) {
                vs += __shfl_xor(vs, o, 64);
                vq += __shfl_xor(vq, o, 64);
            }
            if (l == 0) { sRed[w][r][0] = vs; sRed[w][r][1] = vq; }
        }
        __syncthreads();
        float g = lng[t], bb = lnb[t];
        #pragma unroll
        for (int r = 0; r < 8; ++r) {
            float S = sRed[0][r][0] + sRed[1][r][0] + sRed[2][r][0] + sRed[3][r][0];
            float Q = sRed[0][r][1] + sRed[1][r][1] + sRed[2][r][1] + sRed[3][r][1];
            float mu  = S * (1.f / 256.f);
            float var = Q * (1.f / 256.f) - mu * mu;
            float rs  = rsqrtf(var + 1e-5f);
            sX[r][t] = (xv[r] - mu) * rs * g + bb;
        }
    }
    __syncthreads();

    // stage C: h1 = relu([x | src] @ fc1w^T + fc1b)
    {
        float acc[8] = {0.f,0.f,0.f,0.f,0.f,0.f,0.f,0.f};
        const ushort16* wr = wbf + WOFF_FC1 + (size_t)t * 512;
        for (int kc = 0; kc < 256; kc += 8) {
            uint4 w8 = *(const uint4*)(wr + kc);
            float wf[8]; unpack8(w8, wf);
            #pragma unroll
            for (int r = 0; r < 8; ++r) acc[r] = dot8(&sX[r][kc], wf, acc[r]);
        }
        for (int kc = 0; kc < 256; kc += 8) {
            uint4 w8 = *(const uint4*)(wr + 256 + kc);
            float wf[8]; unpack8(w8, wf);
            #pragma unroll
            for (int r = 0; r < 8; ++r) acc[r] = dot8(&sS[r][kc], wf, acc[r]);
        }
        float bb = fc1b[t];
        #pragma unroll
        for (int r = 0; r < 8; ++r) sH[r][t] = fmaxf(acc[r] + bb, 0.f);
    }
    __syncthreads();

    // stage D: z = h1 @ fc2w^T + fc2b
    {
        float acc[8] = {0.f,0.f,0.f,0.f,0.f,0.f,0.f,0.f};
        const ushort16* wr = wbf + WOFF_FC2 + (size_t)t * DM;
        for (int kc = 0; kc < DM; kc += 8) {
            uint4 w8 = *(const uint4*)(wr + kc);
            float wf[8]; unpack8(w8, wf);
            #pragma unroll
            for (int r = 0; r < 8; ++r) acc[r] = dot8(&sH[r][kc], wf, acc[r]);
        }
        float bb = fc2b[t];
        #pragma unroll
        for (int r = 0; r < 8; ++r)
            zout[(size_t)(b0 + r) * DM + t] = acc[r] + bb;
    }
}

// ---- launch ----------------------------------------------------------------
extern "C" void kernel_launch(void* const* d_in, const int* in_sizes, int n_in,
                              void* d_out, int out_size, void* d_ws, size_t ws_size,
                              hipStream_t stream)
{
    const float* src  = (const float*)d_in[0];
    const float* seq  = (const float*)d_in[1];
    const int*   mask = (const int*)d_in[2];
    const float* wqs  = (const float*)d_in[3];
    const float* wks  = (const float*)d_in[4];
    const float* wvs  = (const float*)d_in[5];
    const float* fcw  = (const float*)d_in[6];
    const float* fcb  = (const float*)d_in[7];
    const float* lng  = (const float*)d_in[8];
    const float* lnb  = (const float*)d_in[9];
    const float* fc1w = (const float*)d_in[10];
    const float* fc1b = (const float*)d_in[11];
    const float* fc2w = (const float*)d_in[12];
    const float* fc2b = (const float*)d_in[13];

    float* zout     = (float*)d_out;
    float* attn_out = zout + (size_t)BATCH * DM;      // z first, then attn

    float* u = (float*)d_ws;                          // 2048*1024 f32 = 8 MB
    float* cbuf = u + (size_t)BATCH * 1024;           // 2048*1024 f32 = 8 MB
    ushort16* wbf = (ushort16*)(cbuf + (size_t)BATCH * 1024);  // 458752 bf16

    prep_kernel<<<448, 256, 0, stream>>>(wqs, wks, wvs, fcw, fc1w, fc2w, wbf);
    qu_kernel<<<256, 256, 0, stream>>>(src, wbf, u);
    attn_kernel<<<BATCH, 256, 0, stream>>>(seq, mask, u, cbuf, attn_out);
    mlp_kernel<<<256, 256, 0, stream>>>(cbuf, src, wbf, fcb, lng, lnb,
                                        fc1b, fc2b, zout);
}